// Round 14
// baseline (422.238 us; speedup 1.0000x reference)
//
#include <hip/hip_runtime.h>
#include <hip/hip_bf16.h>

typedef unsigned int uint;
typedef unsigned short ushort;
typedef _Float16 f16x8 __attribute__((ext_vector_type(8)));
typedef short bf16x8 __attribute__((ext_vector_type(8)));
typedef float f32x4 __attribute__((ext_vector_type(4)));
typedef uint u32x4 __attribute__((ext_vector_type(4)));

#define NE 800000
#define NN 100000
#define TE 64
#define ASTR 160   // ushort row stride of input plane (320 B) — k<160, KC=5 exact
#define HSTR 136   // ushort row stride of hidden planes (272 B)
#define SA 164     // f32 row stride (gather-fallback kernel)
#define SH 132

// packed fp16 weight offsets (ushort elems) in d_ws — R11 layout (verified):
// idx = base + ((np*KC + kc)*2 + i)*512 + lane*8 + j     (single fp16 plane)
// value = fp16( W[k = kc*32 + (lane>>4)*8 + j][n = np*32 + i*16 + (lane&15)] )
#define F0_OFF 0
#define F1_OFF 20480
#define F2_OFF 36864
#define T0_OFF 45056
#define T1_OFF 65536
#define T2_OFF 81920
#define WPK_TOTAL 90112
#define WPK_BYTES (WPK_TOTAL * 2)

#define MF(a, b, c) __builtin_amdgcn_mfma_f32_16x16x32_f16(a, b, c, 0, 0, 0)

// clamp-free tanh: x->+inf => e=inf, rcp=0 => 1; x->-inf => e=0, rcp(1)=1 => -1.
__device__ __forceinline__ float ftanh(float x) {
    float e = __builtin_amdgcn_exp2f(x * 2.885390081777927f);   // exp(2x)
    return __builtin_fmaf(-2.f, __builtin_amdgcn_rcpf(e + 1.f), 1.f);
}

// pack two fp32 -> one u32 of 2 fp16 (RTNE)
__device__ __forceinline__ uint pkh(float a, float b) {
    _Float16 ha = (_Float16)a, hb = (_Float16)b;
    return (uint)__builtin_bit_cast(ushort, ha) |
           ((uint)__builtin_bit_cast(ushort, hb) << 16);
}

// bf16 split (gather-fallback kernel only)
__device__ __forceinline__ void bfsplit(float x, ushort& hi, ushort& lo) {
    uint xb = __builtin_bit_cast(uint, x);
    hi = (ushort)(xb >> 16);
    float hif = __builtin_bit_cast(float, xb & 0xFFFF0000u);
    float res = x - hif;
    lo = (ushort)(__builtin_bit_cast(uint, res) >> 16);
}

__device__ __forceinline__ void split8(const float* v, bf16x8& fh, bf16x8& fl) {
    u32x4 H, L;
#pragma unroll
    for (int i = 0; i < 4; ++i) {
        ushort h0, l0, h1, l1;
        bfsplit(v[2*i],   h0, l0);
        bfsplit(v[2*i+1], h1, l1);
        H[i] = (uint)h0 | ((uint)h1 << 16);
        L[i] = (uint)l0 | ((uint)l1 << 16);
    }
    fh = __builtin_bit_cast(bf16x8, H);
    fl = __builtin_bit_cast(bf16x8, L);
}

// ---- weight pack: single fp16 plane, wave-contiguous — unchanged from R11 ----
__global__ __launch_bounds__(256) void pack_w(
    const float* __restrict__ fW0, const float* __restrict__ fW1, const float* __restrict__ fW2,
    const float* __restrict__ tW0, const float* __restrict__ tW1, const float* __restrict__ tW2,
    ushort* __restrict__ wpk)
{
    int idx = blockIdx.x * 256 + threadIdx.x;   // < WPK_TOTAL
    const float* src; int NP, KC, Kact, base;
    if      (idx < F1_OFF) { src = fW0; NP = 4; KC = 5; Kact = 153; base = F0_OFF; }
    else if (idx < F2_OFF) { src = fW1; NP = 4; KC = 4; Kact = 128; base = F1_OFF; }
    else if (idx < T0_OFF) { src = fW2; NP = 2; KC = 4; Kact = 128; base = F2_OFF; }
    else if (idx < T1_OFF) { src = tW0; NP = 4; KC = 5; Kact = 153; base = T0_OFF; }
    else if (idx < T2_OFF) { src = tW1; NP = 4; KC = 4; Kact = 128; base = T1_OFF; }
    else                   { src = tW2; NP = 2; KC = 4; Kact = 128; base = T2_OFF; }
    int rel  = idx - base;
    int j    = rel & 7;
    int lane = (rel >> 3) & 63;
    int sub  = rel >> 9;
    int i    = sub & 1;
    int s2   = sub >> 1;
    int kc   = s2 % KC;
    int np   = s2 / KC;
    int k = kc * 32 + ((lane >> 4) << 3) + j;
    int n = np * 32 + i * 16 + (lane & 15);
    int N = NP * 32;
    float w = (k < Kact) ? src[(size_t)k * N + n] : 0.f;
    _Float16 h = (_Float16)w;   // RTNE
    wpk[idx] = __builtin_bit_cast(ushort, h);
}

// ---- single-plane K-loop: 32 rows x 64 cols per wave, acc += A*W ----
template<int KC>
__device__ __forceinline__ void kloop1(const ushort* __restrict__ ap, int astr,
                                       const ushort* __restrict__ gWl,
                                       f32x4 (&acc)[2][2])
{
#pragma unroll
    for (int kc = 0; kc < KC; ++kc) {
        f16x8 a0 = *(const f16x8*)(ap + kc * 32);
        f16x8 a1 = *(const f16x8*)(ap + 16 * astr + kc * 32);
        f16x8 w0 = *(const f16x8*)(gWl + kc * 1024);
        f16x8 w1 = *(const f16x8*)(gWl + kc * 1024 + 512);
        acc[0][0] = MF(a0, w0, acc[0][0]);
        acc[1][0] = MF(a1, w0, acc[1][0]);
        acc[0][1] = MF(a0, w1, acc[0][1]);
        acc[1][1] = MF(a1, w1, acc[1][1]);
    }
}

__device__ __forceinline__ void acc_init(f32x4 (&acc)[2][2],
                                         const float* __restrict__ bias,
                                         int npv, int nn)
{
#pragma unroll
    for (int ni = 0; ni < 2; ++ni) {
        float bv = bias[npv * 32 + ni * 16 + nn];
#pragma unroll
        for (int mi = 0; mi < 2; ++mi)
#pragma unroll
            for (int r = 0; r < 4; ++r) acc[mi][ni][r] = bv;
    }
}

__device__ __forceinline__ void epi_store(const f32x4 (&acc)[2][2],
                                          ushort* __restrict__ sO, int ostr,
                                          int mt, int nn, int kq, int npv)
{
#pragma unroll
    for (int mi = 0; mi < 2; ++mi)
#pragma unroll
        for (int ni = 0; ni < 2; ++ni) {
            int n = npv * 32 + ni * 16 + nn;
#pragma unroll
            for (int r = 0; r < 4; ++r) {
                int m = mt * 32 + mi * 16 + kq * 4 + r;   // C/D row map
                _Float16 hh = (_Float16)ftanh(acc[mi][ni][r]);
                sO[m * ostr + n] = __builtin_bit_cast(ushort, hh);
            }
        }
}

// ================= packed-weight main kernel (4 blocks/CU) =================
__global__ __launch_bounds__(512, 8) void edge_mlp_packed(
    const int* __restrict__ af_, const int* __restrict__ at_,
    const float* __restrict__ h_local, const float* __restrict__ h_global,
    const float* __restrict__ x_local, const float* __restrict__ x_global,
    const float* __restrict__ tsc,
    const float* __restrict__ fb0, const float* __restrict__ fb1, const float* __restrict__ fb2,
    const float* __restrict__ tb0, const float* __restrict__ tb1, const float* __restrict__ tb2,
    const ushort* __restrict__ wpk, float* __restrict__ out)
{
    __shared__ ushort sAh[TE * ASTR];   // 20480 B; re-used as t-hidden after Phase A
    __shared__ ushort sHf[TE * HSTR];   // 17408 B
    __shared__ int s_af[TE], s_at[TE];  // 512 B  -> total 38400 B -> 4 blocks/CU
    ushort* sAt = sAh;                  // alias: t-MLP hidden plane

    const int tid = threadIdx.x;
    const int e = tid >> 3, part = tid & 7;
    const int eg = blockIdx.x * TE + e;
    {
        int af = af_[eg], at = at_[eg];
        if (part == 0) { s_af[e] = af; s_at[e] = at; }
        int node = (part < 4) ? af : at;
        int k0 = ((part & 3) << 4) + ((part < 4) ? 0 : 64);
        const float4* hp = (const float4*)(h_local + (size_t)node * 64 + ((part & 3) << 4));
        float4 q0 = hp[0], q1 = hp[1], q2 = hp[2], q3 = hp[3];
        u32x4 H0, H1;
        H0[0] = pkh(q0.x, q0.y); H0[1] = pkh(q0.z, q0.w);
        H0[2] = pkh(q1.x, q1.y); H0[3] = pkh(q1.z, q1.w);
        H1[0] = pkh(q2.x, q2.y); H1[1] = pkh(q2.z, q2.w);
        H1[2] = pkh(q3.x, q3.y); H1[3] = pkh(q3.z, q3.w);
        *(u32x4*)(sAh + e * ASTR + k0)     = H0;
        *(u32x4*)(sAh + e * ASTR + k0 + 8) = H1;
        if (part < 2) {
            int k0t = 128 + part * 16;
            float w[16];
#pragma unroll
            for (int i = 0; i < 16; ++i) {
                int k = k0t + i;
                float x;
                if      (k < 132)  x = x_local[(size_t)eg * 4 + (k - 128)];
                else if (k < 148)  x = h_global[k - 132];
                else if (k < 152)  x = x_global[k - 148];
                else if (k == 152) x = tsc[0];
                else               x = 0.f;
                w[i] = x;
            }
            u32x4 H2, H3;
#pragma unroll
            for (int i = 0; i < 4; ++i) H2[i] = pkh(w[2*i], w[2*i+1]);
#pragma unroll
            for (int i = 0; i < 4; ++i) H3[i] = pkh(w[8+2*i], w[8+2*i+1]);
            *(u32x4*)(sAh + e * ASTR + k0t)     = H2;
            *(u32x4*)(sAh + e * ASTR + k0t + 8) = H3;
        }
    }
    __syncthreads();

    const int lane = tid & 63;
    const int wave = tid >> 6;
    const int mt   = wave >> 2;          // 0..1  (32-edge row tile)
    const int np   = wave & 3;           // 0..3  (32-col tile)
    const int nn   = lane & 15;
    const int kq   = (lane >> 4) & 3;
    const int npu  = __builtin_amdgcn_readfirstlane(np);

    // ---- Phase A: L0 for both MLPs, shared single-plane A fragments ----
    {
        f32x4 af[2][2], at2[2][2];
        acc_init(af,  fb0, np, nn);
        acc_init(at2, tb0, np, nn);
        const ushort* ap = sAh + (mt * 32 + nn) * ASTR + kq * 8;
        const ushort* gF = wpk + F0_OFF + npu * (5 * 1024) + lane * 8;
        const ushort* gT = wpk + T0_OFF + npu * (5 * 1024) + lane * 8;
#pragma unroll
        for (int kc = 0; kc < 5; ++kc) {
            f16x8 a0 = *(const f16x8*)(ap + kc * 32);
            f16x8 a1 = *(const f16x8*)(ap + 16 * ASTR + kc * 32);
            f16x8 w0 = *(const f16x8*)(gF + kc * 1024);
            f16x8 w1 = *(const f16x8*)(gF + kc * 1024 + 512);
            f16x8 u0 = *(const f16x8*)(gT + kc * 1024);
            f16x8 u1 = *(const f16x8*)(gT + kc * 1024 + 512);
            af[0][0]  = MF(a0, w0, af[0][0]);  af[1][0]  = MF(a1, w0, af[1][0]);
            af[0][1]  = MF(a0, w1, af[0][1]);  af[1][1]  = MF(a1, w1, af[1][1]);
            at2[0][0] = MF(a0, u0, at2[0][0]); at2[1][0] = MF(a1, u0, at2[1][0]);
            at2[0][1] = MF(a0, u1, at2[0][1]); at2[1][1] = MF(a1, u1, at2[1][1]);
        }
        epi_store(af, sHf, HSTR, mt, nn, kq, np);   // sHf fresh, safe pre-barrier
        __syncthreads();                            // all sAh reads done
        epi_store(at2, sAt, HSTR, mt, nn, kq, np);  // overwrite dead sA region
    }
    __syncthreads();

    // ---- Phase B: L1 for both MLPs (in-place on sHf/sAt) ----
    {
        f32x4 af[2][2], at2[2][2];
        acc_init(af,  fb1, np, nn);
        acc_init(at2, tb1, np, nn);
        const ushort* apf = sHf + (mt * 32 + nn) * HSTR + kq * 8;
        const ushort* apt = sAt + (mt * 32 + nn) * HSTR + kq * 8;
        kloop1<4>(apf, HSTR, wpk + F1_OFF + npu * 4096 + lane * 8, af);
        kloop1<4>(apt, HSTR, wpk + T1_OFF + npu * 4096 + lane * 8, at2);
        __syncthreads();   // all reads done before in-place overwrite
        epi_store(af,  sHf, HSTR, mt, nn, kq, np);
        epi_store(at2, sAt, HSTR, mt, nn, kq, np);
    }
    __syncthreads();

    // ---- Phase C: L2 scatter, wave-split (np<2 -> f, np>=2 -> t) ----
    {
        const int sel = __builtin_amdgcn_readfirstlane(np >> 1);
        const int np2 = __builtin_amdgcn_readfirstlane(np & 1);
        const ushort* sH  = sel ? sAt : sHf;
        const ushort* gW2 = wpk + (sel ? T2_OFF : F2_OFF) + np2 * 4096 + lane * 8;
        const float* b2   = sel ? tb2 : fb2;
        const int* nds    = sel ? s_at : s_af;

        f32x4 acc[2][2];
        acc_init(acc, b2, np2, nn);
        const ushort* ap = sH + (mt * 32 + nn) * HSTR + kq * 8;
        kloop1<4>(ap, HSTR, gW2, acc);
#pragma unroll
        for (int mi = 0; mi < 2; ++mi)
#pragma unroll
            for (int ni = 0; ni < 2; ++ni) {
                int n = np2 * 32 + ni * 16 + nn;
#pragma unroll
                for (int r = 0; r < 4; ++r) {
                    int m = mt * 32 + mi * 16 + kq * 4 + r;
                    float h = ftanh(acc[mi][ni][r]);
                    unsafeAtomicAdd(out + (size_t)nds[m] * 64 + n, h);
                }
            }
    }
}

// ================= gather fallback (R4, verified passing; bf16 3-chain) =================
template<int KC, int NT, int KACT, bool SCATTER>
__device__ __forceinline__ void layer(
    const float* __restrict__ sA, int astr,
    const float* __restrict__ gW, const float* __restrict__ bias,
    float* __restrict__ sO,
    float* __restrict__ out, const int* __restrict__ s_nodes, int tid)
{
    constexpr int NTW = NT / 2;
    constexpr int N = NT * 16;
    const int lane = tid & 63;
    const int wave = tid >> 6;
    const int mt   = wave >> 1;
    const int ntb  = (wave & 1) * NTW;
    const int arow = mt * 16 + (lane & 15);
    const int kg   = (lane >> 4) * 8;
    const int nn   = lane & 15;

    f32x4 aHH[NTW], aLH[NTW], aHL[NTW];
#pragma unroll
    for (int i = 0; i < NTW; ++i)
#pragma unroll
        for (int r = 0; r < 4; ++r) { aHH[i][r] = 0.f; aLH[i][r] = 0.f; aHL[i][r] = 0.f; }

#pragma unroll
    for (int kc = 0; kc < KC; ++kc) {
        const float* ap = sA + arow * astr + kc * 32 + kg;
        float av[8];
        float4 a0 = *(const float4*)ap;
        float4 a1 = *(const float4*)(ap + 4);
        av[0]=a0.x; av[1]=a0.y; av[2]=a0.z; av[3]=a0.w;
        av[4]=a1.x; av[5]=a1.y; av[6]=a1.z; av[7]=a1.w;
        bf16x8 ah, al; split8(av, ah, al);
#pragma unroll
        for (int i = 0; i < NTW; ++i) {
            int n = (ntb + i) * 16 + nn;
            float wv[8];
#pragma unroll
            for (int j = 0; j < 8; ++j) {
                int k = kc * 32 + kg + j;
                float w = 0.f;
                if (KC * 32 <= KACT || k < KACT)
                    w = gW[(size_t)k * N + n];
                wv[j] = w;
            }
            bf16x8 bh, bl; split8(wv, bh, bl);
            aHH[i] = __builtin_amdgcn_mfma_f32_16x16x32_bf16(ah, bh, aHH[i], 0, 0, 0);
            aLH[i] = __builtin_amdgcn_mfma_f32_16x16x32_bf16(al, bh, aLH[i], 0, 0, 0);
            aHL[i] = __builtin_amdgcn_mfma_f32_16x16x32_bf16(ah, bl, aHL[i], 0, 0, 0);
        }
    }

    if (!SCATTER) __syncthreads();

#pragma unroll
    for (int i = 0; i < NTW; ++i) {
        int n = (ntb + i) * 16 + nn;
        float bv = bias[n];
#pragma unroll
        for (int r = 0; r < 4; ++r) {
            int m = mt * 16 + ((lane >> 4) << 2) + r;
            float h = ftanh(aHH[i][r] + aLH[i][r] + aHL[i][r] + bv);
            if (SCATTER) {
                unsafeAtomicAdd(out + (size_t)s_nodes[m] * 64 + n, h);
            } else {
                sO[m * SH + n] = h;
            }
        }
    }
}

__global__ __launch_bounds__(512) void edge_mlp_gather(
    const int* __restrict__ af_, const int* __restrict__ at_,
    const float* __restrict__ h_local, const float* __restrict__ h_global,
    const float* __restrict__ x_local, const float* __restrict__ x_global,
    const float* __restrict__ tsc,
    const float* __restrict__ fW0, const float* __restrict__ fb0,
    const float* __restrict__ fW1, const float* __restrict__ fb1,
    const float* __restrict__ fW2, const float* __restrict__ fb2,
    const float* __restrict__ tW0, const float* __restrict__ tb0,
    const float* __restrict__ tW1, const float* __restrict__ tb1,
    const float* __restrict__ tW2, const float* __restrict__ tb2,
    float* __restrict__ out)
{
    __shared__ float sA[TE * SA];
    __shared__ float sH[TE * SH];
    __shared__ int s_af[TE], s_at[TE];

    const int tid = threadIdx.x;
    const int e = tid >> 3, part = tid & 7;
    const int eg = blockIdx.x * TE + e;
    {
        int af = af_[eg], at = at_[eg];
        if (part == 0) { s_af[e] = af; s_at[e] = at; }
        int node = (part < 4) ? af : at;
        int k0 = ((part & 3) << 4) + ((part < 4) ? 0 : 64);
        const float4* hp = (const float4*)(h_local + (size_t)node * 64 + ((part & 3) << 4));
        float4* dst = (float4*)(sA + e * SA + k0);
        dst[0] = hp[0]; dst[1] = hp[1]; dst[2] = hp[2]; dst[3] = hp[3];
        if (part < 2) {
            int k0t = 128 + part * 16;
#pragma unroll
            for (int i = 0; i < 16; ++i) {
                int k = k0t + i;
                float x;
                if      (k < 132)  x = x_local[(size_t)eg * 4 + (k - 128)];
                else if (k < 148)  x = h_global[k - 132];
                else if (k < 152)  x = x_global[k - 148];
                else if (k == 152) x = tsc[0];
                else               x = 0.f;
                sA[e * SA + k] = x;
            }
        }
    }
    __syncthreads();
    layer<5,8,153,false>(sA, SA, fW0, fb0, sH, nullptr, nullptr, tid);
    __syncthreads();
    layer<4,8,128,false>(sH, SH, fW1, fb1, sH, nullptr, nullptr, tid);
    __syncthreads();
    layer<4,4,128,true >(sH, SH, fW2, fb2, nullptr, out, s_af, tid);
    __syncthreads();
    layer<5,8,153,false>(sA, SA, tW0, tb0, sH, nullptr, nullptr, tid);
    __syncthreads();
    layer<4,8,128,false>(sH, SH, tW1, tb1, sH, nullptr, nullptr, tid);
    __syncthreads();
    layer<4,4,128,true >(sH, SH, tW2, tb2, nullptr, out, s_at, tid);
}

__global__ __launch_bounds__(256) void tanh_kernel(float* __restrict__ out, int n4) {
    int i = blockIdx.x * blockDim.x + threadIdx.x;
    int stride = gridDim.x * blockDim.x;
    float4* p = (float4*)out;
    for (; i < n4; i += stride) {
        float4 v = p[i];
        v.x = ftanh(v.x); v.y = ftanh(v.y); v.z = ftanh(v.z); v.w = ftanh(v.w);
        p[i] = v;
    }
}

extern "C" void kernel_launch(void* const* d_in, const int* in_sizes, int n_in,
                              void* d_out, int out_size, void* d_ws, size_t ws_size,
                              hipStream_t stream) {
    const int*   addr_from = (const int*)d_in[0];
    const int*   addr_to   = (const int*)d_in[1];
    const float* h_local   = (const float*)d_in[2];
    const float* h_global  = (const float*)d_in[3];
    const float* x_local   = (const float*)d_in[4];
    const float* x_global  = (const float*)d_in[5];
    const float* tsc       = (const float*)d_in[6];
    const float* fW0 = (const float*)d_in[7];
    const float* fb0 = (const float*)d_in[8];
    const float* fW1 = (const float*)d_in[9];
    const float* fb1 = (const float*)d_in[10];
    const float* fW2 = (const float*)d_in[11];
    const float* fb2 = (const float*)d_in[12];
    const float* tW0 = (const float*)d_in[13];
    const float* tb0 = (const float*)d_in[14];
    const float* tW1 = (const float*)d_in[15];
    const float* tb1 = (const float*)d_in[16];
    const float* tW2 = (const float*)d_in[17];
    const float* tb2 = (const float*)d_in[18];
    float* out = (float*)d_out;

    hipMemsetAsync(d_out, 0, (size_t)NN * 64 * sizeof(float), stream);

    if (ws_size >= (size_t)WPK_BYTES) {
        ushort* wpk = (ushort*)d_ws;
        pack_w<<<WPK_TOTAL / 256, 256, 0, stream>>>(fW0, fW1, fW2, tW0, tW1, tW2, wpk);
        edge_mlp_packed<<<NE / TE, 512, 0, stream>>>(
            addr_from, addr_to, h_local, h_global, x_local, x_global, tsc,
            fb0, fb1, fb2, tb0, tb1, tb2, wpk, out);
    } else {
        edge_mlp_gather<<<NE / TE, 512, 0, stream>>>(
            addr_from, addr_to, h_local, h_global, x_local, x_global, tsc,
            fW0, fb0, fW1, fb1, fW2, fb2, tW0, tb0, tW1, tb1, tW2, tb2, out);
    }
    tanh_kernel<<<2048, 256, 0, stream>>>(out, NN * 64 / 4);
}

// Round 15
// 391.231 us; speedup vs baseline: 1.0793x; 1.0793x over previous
//
#include <hip/hip_runtime.h>
#include <hip/hip_bf16.h>

typedef unsigned int uint;
typedef unsigned short ushort;
typedef _Float16 f16x8 __attribute__((ext_vector_type(8)));
typedef short bf16x8 __attribute__((ext_vector_type(8)));
typedef float f32x4 __attribute__((ext_vector_type(4)));
typedef uint u32x4 __attribute__((ext_vector_type(4)));

#define NE 800000
#define NN 100000
#define TE 64
#define ASTR 160   // ushort row stride of input plane (320 B) — k<160, KC=5 exact
#define HSTR 136   // ushort row stride of hidden planes (272 B)
#define SA 164     // f32 row stride (gather-fallback kernel)
#define SH 132

// packed fp16 weight offsets (ushort elems) in d_ws — R11 layout (verified):
// idx = base + ((np*KC + kc)*2 + i)*512 + lane*8 + j     (single fp16 plane)
// value = fp16( W[k = kc*32 + (lane>>4)*8 + j][n = np*32 + i*16 + (lane&15)] )
#define F0_OFF 0
#define F1_OFF 20480
#define F2_OFF 36864
#define T0_OFF 45056
#define T1_OFF 65536
#define T2_OFF 81920
#define WPK_TOTAL 90112
#define WPK_BYTES (WPK_TOTAL * 2)

#define MF(a, b, c) __builtin_amdgcn_mfma_f32_16x16x32_f16(a, b, c, 0, 0, 0)

// clamp-free tanh: x->+inf => e=inf, rcp=0 => 1; x->-inf => e=0, rcp(1)=1 => -1.
__device__ __forceinline__ float ftanh(float x) {
    float e = __builtin_amdgcn_exp2f(x * 2.885390081777927f);   // exp(2x)
    return __builtin_fmaf(-2.f, __builtin_amdgcn_rcpf(e + 1.f), 1.f);
}

// pack two fp32 -> one u32 of 2 fp16 (RTNE)
__device__ __forceinline__ uint pkh(float a, float b) {
    _Float16 ha = (_Float16)a, hb = (_Float16)b;
    return (uint)__builtin_bit_cast(ushort, ha) |
           ((uint)__builtin_bit_cast(ushort, hb) << 16);
}

// bf16 split (gather-fallback kernel only)
__device__ __forceinline__ void bfsplit(float x, ushort& hi, ushort& lo) {
    uint xb = __builtin_bit_cast(uint, x);
    hi = (ushort)(xb >> 16);
    float hif = __builtin_bit_cast(float, xb & 0xFFFF0000u);
    float res = x - hif;
    lo = (ushort)(__builtin_bit_cast(uint, res) >> 16);
}

__device__ __forceinline__ void split8(const float* v, bf16x8& fh, bf16x8& fl) {
    u32x4 H, L;
#pragma unroll
    for (int i = 0; i < 4; ++i) {
        ushort h0, l0, h1, l1;
        bfsplit(v[2*i],   h0, l0);
        bfsplit(v[2*i+1], h1, l1);
        H[i] = (uint)h0 | ((uint)h1 << 16);
        L[i] = (uint)l0 | ((uint)l1 << 16);
    }
    fh = __builtin_bit_cast(bf16x8, H);
    fl = __builtin_bit_cast(bf16x8, L);
}

// ---- weight pack: single fp16 plane, wave-contiguous — unchanged from R11 ----
__global__ __launch_bounds__(256) void pack_w(
    const float* __restrict__ fW0, const float* __restrict__ fW1, const float* __restrict__ fW2,
    const float* __restrict__ tW0, const float* __restrict__ tW1, const float* __restrict__ tW2,
    ushort* __restrict__ wpk)
{
    int idx = blockIdx.x * 256 + threadIdx.x;   // < WPK_TOTAL
    const float* src; int NP, KC, Kact, base;
    if      (idx < F1_OFF) { src = fW0; NP = 4; KC = 5; Kact = 153; base = F0_OFF; }
    else if (idx < F2_OFF) { src = fW1; NP = 4; KC = 4; Kact = 128; base = F1_OFF; }
    else if (idx < T0_OFF) { src = fW2; NP = 2; KC = 4; Kact = 128; base = F2_OFF; }
    else if (idx < T1_OFF) { src = tW0; NP = 4; KC = 5; Kact = 153; base = T0_OFF; }
    else if (idx < T2_OFF) { src = tW1; NP = 4; KC = 4; Kact = 128; base = T1_OFF; }
    else                   { src = tW2; NP = 2; KC = 4; Kact = 128; base = T2_OFF; }
    int rel  = idx - base;
    int j    = rel & 7;
    int lane = (rel >> 3) & 63;
    int sub  = rel >> 9;
    int i    = sub & 1;
    int s2   = sub >> 1;
    int kc   = s2 % KC;
    int np   = s2 / KC;
    int k = kc * 32 + ((lane >> 4) << 3) + j;
    int n = np * 32 + i * 16 + (lane & 15);
    int N = NP * 32;
    float w = (k < Kact) ? src[(size_t)k * N + n] : 0.f;
    _Float16 h = (_Float16)w;   // RTNE
    wpk[idx] = __builtin_bit_cast(ushort, h);
}

// ---- single-plane K-loop: 32 rows x 64 cols per wave, acc += A*W ----
template<int KC>
__device__ __forceinline__ void kloop1(const ushort* __restrict__ ap, int astr,
                                       const ushort* __restrict__ gWl,
                                       f32x4 (&acc)[2][2])
{
#pragma unroll
    for (int kc = 0; kc < KC; ++kc) {
        f16x8 a0 = *(const f16x8*)(ap + kc * 32);
        f16x8 a1 = *(const f16x8*)(ap + 16 * astr + kc * 32);
        f16x8 w0 = *(const f16x8*)(gWl + kc * 1024);
        f16x8 w1 = *(const f16x8*)(gWl + kc * 1024 + 512);
        acc[0][0] = MF(a0, w0, acc[0][0]);
        acc[1][0] = MF(a1, w0, acc[1][0]);
        acc[0][1] = MF(a0, w1, acc[0][1]);
        acc[1][1] = MF(a1, w1, acc[1][1]);
    }
}

__device__ __forceinline__ void acc_init(f32x4 (&acc)[2][2],
                                         const float* __restrict__ bias,
                                         int npv, int nn)
{
#pragma unroll
    for (int ni = 0; ni < 2; ++ni) {
        float bv = bias[npv * 32 + ni * 16 + nn];
#pragma unroll
        for (int mi = 0; mi < 2; ++mi)
#pragma unroll
            for (int r = 0; r < 4; ++r) acc[mi][ni][r] = bv;
    }
}

__device__ __forceinline__ void epi_store(const f32x4 (&acc)[2][2],
                                          ushort* __restrict__ sO, int ostr,
                                          int mt, int nn, int kq, int npv)
{
#pragma unroll
    for (int mi = 0; mi < 2; ++mi)
#pragma unroll
        for (int ni = 0; ni < 2; ++ni) {
            int n = npv * 32 + ni * 16 + nn;
#pragma unroll
            for (int r = 0; r < 4; ++r) {
                int m = mt * 32 + mi * 16 + kq * 4 + r;   // C/D row map
                _Float16 hh = (_Float16)ftanh(acc[mi][ni][r]);
                sO[m * ostr + n] = __builtin_bit_cast(ushort, hh);
            }
        }
}

// ================= packed-weight main kernel (3 blocks/CU, no spills) =================
__global__ __launch_bounds__(512, 6) void edge_mlp_packed(
    const int* __restrict__ af_, const int* __restrict__ at_,
    const float* __restrict__ h_local, const float* __restrict__ h_global,
    const float* __restrict__ x_local, const float* __restrict__ x_global,
    const float* __restrict__ tsc,
    const float* __restrict__ fb0, const float* __restrict__ fb1, const float* __restrict__ fb2,
    const float* __restrict__ tb0, const float* __restrict__ tb1, const float* __restrict__ tb2,
    const ushort* __restrict__ wpk, float* __restrict__ out)
{
    __shared__ ushort sAh[TE * ASTR];   // 20480 B; re-used as t-hidden after Phase A
    __shared__ ushort sHf[TE * HSTR];   // 17408 B
    __shared__ int s_af[TE], s_at[TE];  // 512 B  -> total 38400 B
    ushort* sAt = sAh;                  // alias: t-MLP hidden plane

    const int tid = threadIdx.x;
    const int e = tid >> 3, part = tid & 7;
    const int eg = blockIdx.x * TE + e;
    {
        int af = af_[eg], at = at_[eg];
        if (part == 0) { s_af[e] = af; s_at[e] = at; }
        int node = (part < 4) ? af : at;
        int k0 = ((part & 3) << 4) + ((part < 4) ? 0 : 64);
        const float4* hp = (const float4*)(h_local + (size_t)node * 64 + ((part & 3) << 4));
        float4 q0 = hp[0], q1 = hp[1], q2 = hp[2], q3 = hp[3];
        u32x4 H0, H1;
        H0[0] = pkh(q0.x, q0.y); H0[1] = pkh(q0.z, q0.w);
        H0[2] = pkh(q1.x, q1.y); H0[3] = pkh(q1.z, q1.w);
        H1[0] = pkh(q2.x, q2.y); H1[1] = pkh(q2.z, q2.w);
        H1[2] = pkh(q3.x, q3.y); H1[3] = pkh(q3.z, q3.w);
        *(u32x4*)(sAh + e * ASTR + k0)     = H0;
        *(u32x4*)(sAh + e * ASTR + k0 + 8) = H1;
        if (part < 2) {
            int k0t = 128 + part * 16;
            float w[16];
#pragma unroll
            for (int i = 0; i < 16; ++i) {
                int k = k0t + i;
                float x;
                if      (k < 132)  x = x_local[(size_t)eg * 4 + (k - 128)];
                else if (k < 148)  x = h_global[k - 132];
                else if (k < 152)  x = x_global[k - 148];
                else if (k == 152) x = tsc[0];
                else               x = 0.f;
                w[i] = x;
            }
            u32x4 H2, H3;
#pragma unroll
            for (int i = 0; i < 4; ++i) H2[i] = pkh(w[2*i], w[2*i+1]);
#pragma unroll
            for (int i = 0; i < 4; ++i) H3[i] = pkh(w[8+2*i], w[8+2*i+1]);
            *(u32x4*)(sAh + e * ASTR + k0t)     = H2;
            *(u32x4*)(sAh + e * ASTR + k0t + 8) = H3;
        }
    }
    __syncthreads();

    const int lane = tid & 63;
    const int wave = tid >> 6;
    const int mt   = wave >> 2;          // 0..1  (32-edge row tile)
    const int np   = wave & 3;           // 0..3  (32-col tile)
    const int nn   = lane & 15;
    const int kq   = (lane >> 4) & 3;
    const int npu  = __builtin_amdgcn_readfirstlane(np);

    // ---- Phase A: L0 for both MLPs, shared single-plane A fragments ----
    {
        f32x4 af[2][2], at2[2][2];
        acc_init(af,  fb0, np, nn);
        acc_init(at2, tb0, np, nn);
        const ushort* ap = sAh + (mt * 32 + nn) * ASTR + kq * 8;
        const ushort* gF = wpk + F0_OFF + npu * (5 * 1024) + lane * 8;
        const ushort* gT = wpk + T0_OFF + npu * (5 * 1024) + lane * 8;
#pragma unroll
        for (int kc = 0; kc < 5; ++kc) {
            f16x8 a0 = *(const f16x8*)(ap + kc * 32);
            f16x8 a1 = *(const f16x8*)(ap + 16 * ASTR + kc * 32);
            f16x8 w0 = *(const f16x8*)(gF + kc * 1024);
            f16x8 w1 = *(const f16x8*)(gF + kc * 1024 + 512);
            f16x8 u0 = *(const f16x8*)(gT + kc * 1024);
            f16x8 u1 = *(const f16x8*)(gT + kc * 1024 + 512);
            af[0][0]  = MF(a0, w0, af[0][0]);  af[1][0]  = MF(a1, w0, af[1][0]);
            af[0][1]  = MF(a0, w1, af[0][1]);  af[1][1]  = MF(a1, w1, af[1][1]);
            at2[0][0] = MF(a0, u0, at2[0][0]); at2[1][0] = MF(a1, u0, at2[1][0]);
            at2[0][1] = MF(a0, u1, at2[0][1]); at2[1][1] = MF(a1, u1, at2[1][1]);
        }
        epi_store(af, sHf, HSTR, mt, nn, kq, np);   // sHf fresh, safe pre-barrier
        __syncthreads();                            // all sAh reads done
        epi_store(at2, sAt, HSTR, mt, nn, kq, np);  // overwrite dead sA region
    }
    __syncthreads();

    // ---- Phase B: L1 for both MLPs (in-place on sHf/sAt) ----
    {
        f32x4 af[2][2], at2[2][2];
        acc_init(af,  fb1, np, nn);
        acc_init(at2, tb1, np, nn);
        const ushort* apf = sHf + (mt * 32 + nn) * HSTR + kq * 8;
        const ushort* apt = sAt + (mt * 32 + nn) * HSTR + kq * 8;
        kloop1<4>(apf, HSTR, wpk + F1_OFF + npu * 4096 + lane * 8, af);
        kloop1<4>(apt, HSTR, wpk + T1_OFF + npu * 4096 + lane * 8, at2);
        __syncthreads();   // all reads done before in-place overwrite
        epi_store(af,  sHf, HSTR, mt, nn, kq, np);
        epi_store(at2, sAt, HSTR, mt, nn, kq, np);
    }
    __syncthreads();

    // ---- Phase C: L2 scatter, wave-split (np<2 -> f, np>=2 -> t) ----
    {
        const int sel = __builtin_amdgcn_readfirstlane(np >> 1);
        const int np2 = __builtin_amdgcn_readfirstlane(np & 1);
        const ushort* sH  = sel ? sAt : sHf;
        const ushort* gW2 = wpk + (sel ? T2_OFF : F2_OFF) + np2 * 4096 + lane * 8;
        const float* b2   = sel ? tb2 : fb2;
        const int* nds    = sel ? s_at : s_af;

        f32x4 acc[2][2];
        acc_init(acc, b2, np2, nn);
        const ushort* ap = sH + (mt * 32 + nn) * HSTR + kq * 8;
        kloop1<4>(ap, HSTR, gW2, acc);
#pragma unroll
        for (int mi = 0; mi < 2; ++mi)
#pragma unroll
            for (int ni = 0; ni < 2; ++ni) {
                int n = np2 * 32 + ni * 16 + nn;
#pragma unroll
                for (int r = 0; r < 4; ++r) {
                    int m = mt * 32 + mi * 16 + kq * 4 + r;
                    float h = ftanh(acc[mi][ni][r]);
                    unsafeAtomicAdd(out + (size_t)nds[m] * 64 + n, h);
                }
            }
    }
}

// ================= gather fallback (R4, verified passing; bf16 3-chain) =================
template<int KC, int NT, int KACT, bool SCATTER>
__device__ __forceinline__ void layer(
    const float* __restrict__ sA, int astr,
    const float* __restrict__ gW, const float* __restrict__ bias,
    float* __restrict__ sO,
    float* __restrict__ out, const int* __restrict__ s_nodes, int tid)
{
    constexpr int NTW = NT / 2;
    constexpr int N = NT * 16;
    const int lane = tid & 63;
    const int wave = tid >> 6;
    const int mt   = wave >> 1;
    const int ntb  = (wave & 1) * NTW;
    const int arow = mt * 16 + (lane & 15);
    const int kg   = (lane >> 4) * 8;
    const int nn   = lane & 15;

    f32x4 aHH[NTW], aLH[NTW], aHL[NTW];
#pragma unroll
    for (int i = 0; i < NTW; ++i)
#pragma unroll
        for (int r = 0; r < 4; ++r) { aHH[i][r] = 0.f; aLH[i][r] = 0.f; aHL[i][r] = 0.f; }

#pragma unroll
    for (int kc = 0; kc < KC; ++kc) {
        const float* ap = sA + arow * astr + kc * 32 + kg;
        float av[8];
        float4 a0 = *(const float4*)ap;
        float4 a1 = *(const float4*)(ap + 4);
        av[0]=a0.x; av[1]=a0.y; av[2]=a0.z; av[3]=a0.w;
        av[4]=a1.x; av[5]=a1.y; av[6]=a1.z; av[7]=a1.w;
        bf16x8 ah, al; split8(av, ah, al);
#pragma unroll
        for (int i = 0; i < NTW; ++i) {
            int n = (ntb + i) * 16 + nn;
            float wv[8];
#pragma unroll
            for (int j = 0; j < 8; ++j) {
                int k = kc * 32 + kg + j;
                float w = 0.f;
                if (KC * 32 <= KACT || k < KACT)
                    w = gW[(size_t)k * N + n];
                wv[j] = w;
            }
            bf16x8 bh, bl; split8(wv, bh, bl);
            aHH[i] = __builtin_amdgcn_mfma_f32_16x16x32_bf16(ah, bh, aHH[i], 0, 0, 0);
            aLH[i] = __builtin_amdgcn_mfma_f32_16x16x32_bf16(al, bh, aLH[i], 0, 0, 0);
            aHL[i] = __builtin_amdgcn_mfma_f32_16x16x32_bf16(ah, bl, aHL[i], 0, 0, 0);
        }
    }

    if (!SCATTER) __syncthreads();

#pragma unroll
    for (int i = 0; i < NTW; ++i) {
        int n = (ntb + i) * 16 + nn;
        float bv = bias[n];
#pragma unroll
        for (int r = 0; r < 4; ++r) {
            int m = mt * 16 + ((lane >> 4) << 2) + r;
            float h = ftanh(aHH[i][r] + aLH[i][r] + aHL[i][r] + bv);
            if (SCATTER) {
                unsafeAtomicAdd(out + (size_t)s_nodes[m] * 64 + n, h);
            } else {
                sO[m * SH + n] = h;
            }
        }
    }
}

__global__ __launch_bounds__(512) void edge_mlp_gather(
    const int* __restrict__ af_, const int* __restrict__ at_,
    const float* __restrict__ h_local, const float* __restrict__ h_global,
    const float* __restrict__ x_local, const float* __restrict__ x_global,
    const float* __restrict__ tsc,
    const float* __restrict__ fW0, const float* __restrict__ fb0,
    const float* __restrict__ fW1, const float* __restrict__ fb1,
    const float* __restrict__ fW2, const float* __restrict__ fb2,
    const float* __restrict__ tW0, const float* __restrict__ tb0,
    const float* __restrict__ tW1, const float* __restrict__ tb1,
    const float* __restrict__ tW2, const float* __restrict__ tb2,
    float* __restrict__ out)
{
    __shared__ float sA[TE * SA];
    __shared__ float sH[TE * SH];
    __shared__ int s_af[TE], s_at[TE];

    const int tid = threadIdx.x;
    const int e = tid >> 3, part = tid & 7;
    const int eg = blockIdx.x * TE + e;
    {
        int af = af_[eg], at = at_[eg];
        if (part == 0) { s_af[e] = af; s_at[e] = at; }
        int node = (part < 4) ? af : at;
        int k0 = ((part & 3) << 4) + ((part < 4) ? 0 : 64);
        const float4* hp = (const float4*)(h_local + (size_t)node * 64 + ((part & 3) << 4));
        float4* dst = (float4*)(sA + e * SA + k0);
        dst[0] = hp[0]; dst[1] = hp[1]; dst[2] = hp[2]; dst[3] = hp[3];
        if (part < 2) {
            int k0t = 128 + part * 16;
#pragma unroll
            for (int i = 0; i < 16; ++i) {
                int k = k0t + i;
                float x;
                if      (k < 132)  x = x_local[(size_t)eg * 4 + (k - 128)];
                else if (k < 148)  x = h_global[k - 132];
                else if (k < 152)  x = x_global[k - 148];
                else if (k == 152) x = tsc[0];
                else               x = 0.f;
                sA[e * SA + k] = x;
            }
        }
    }
    __syncthreads();
    layer<5,8,153,false>(sA, SA, fW0, fb0, sH, nullptr, nullptr, tid);
    __syncthreads();
    layer<4,8,128,false>(sH, SH, fW1, fb1, sH, nullptr, nullptr, tid);
    __syncthreads();
    layer<4,4,128,true >(sH, SH, fW2, fb2, nullptr, out, s_af, tid);
    __syncthreads();
    layer<5,8,153,false>(sA, SA, tW0, tb0, sH, nullptr, nullptr, tid);
    __syncthreads();
    layer<4,8,128,false>(sH, SH, tW1, tb1, sH, nullptr, nullptr, tid);
    __syncthreads();
    layer<4,4,128,true >(sH, SH, tW2, tb2, nullptr, out, s_at, tid);
}

__global__ __launch_bounds__(256) void tanh_kernel(float* __restrict__ out, int n4) {
    int i = blockIdx.x * blockDim.x + threadIdx.x;
    int stride = gridDim.x * blockDim.x;
    float4* p = (float4*)out;
    for (; i < n4; i += stride) {
        float4 v = p[i];
        v.x = ftanh(v.x); v.y = ftanh(v.y); v.z = ftanh(v.z); v.w = ftanh(v.w);
        p[i] = v;
    }
}

extern "C" void kernel_launch(void* const* d_in, const int* in_sizes, int n_in,
                              void* d_out, int out_size, void* d_ws, size_t ws_size,
                              hipStream_t stream) {
    const int*   addr_from = (const int*)d_in[0];
    const int*   addr_to   = (const int*)d_in[1];
    const float* h_local   = (const float*)d_in[2];
    const float* h_global  = (const float*)d_in[3];
    const float* x_local   = (const float*)d_in[4];
    const float* x_global  = (const float*)d_in[5];
    const float* tsc       = (const float*)d_in[6];
    const float* fW0 = (const float*)d_in[7];
    const float* fb0 = (const float*)d_in[8];
    const float* fW1 = (const float*)d_in[9];
    const float* fb1 = (const float*)d_in[10];
    const float* fW2 = (const float*)d_in[11];
    const float* fb2 = (const float*)d_in[12];
    const float* tW0 = (const float*)d_in[13];
    const float* tb0 = (const float*)d_in[14];
    const float* tW1 = (const float*)d_in[15];
    const float* tb1 = (const float*)d_in[16];
    const float* tW2 = (const float*)d_in[17];
    const float* tb2 = (const float*)d_in[18];
    float* out = (float*)d_out;

    hipMemsetAsync(d_out, 0, (size_t)NN * 64 * sizeof(float), stream);

    if (ws_size >= (size_t)WPK_BYTES) {
        ushort* wpk = (ushort*)d_ws;
        pack_w<<<WPK_TOTAL / 256, 256, 0, stream>>>(fW0, fW1, fW2, tW0, tW1, tW2, wpk);
        edge_mlp_packed<<<NE / TE, 512, 0, stream>>>(
            addr_from, addr_to, h_local, h_global, x_local, x_global, tsc,
            fb0, fb1, fb2, tb0, tb1, tb2, wpk, out);
    } else {
        edge_mlp_gather<<<NE / TE, 512, 0, stream>>>(
            addr_from, addr_to, h_local, h_global, x_local, x_global, tsc,
            fW0, fb0, fW1, fb1, fW2, fb2, tW0, tb0, tW1, tb1, tW2, tb2, out);
    }
    tanh_kernel<<<2048, 256, 0, stream>>>(out, NN * 64 / 4);
}